// Round 10
// baseline (13436.865 us; speedup 1.0000x reference)
//
#include <hip/hip_runtime.h>
#include <math.h>

#define NPTS    16384
#define DIM     128
#define KSEL    16
#define TSEL    18      // per-scanner sorted top list (16 + self + 1 margin)
#define NSCAN   8       // scanners per row (one per half-wave)
#define RPB     32      // rows per block
#define THREADS 256
#define CHUNK   64      // candidate columns staged per LDS chunk (32 KB)
#define NCHUNK  (NPTS / CHUNK)
#define CPS     (CHUNK / NSCAN)  // candidates per scanner per chunk = 8
#define NCAND   (NSCAN * TSEL)   // 144 candidates per row
#define CSTRIDE 145              // padded per-row stride (u64 keys)
#define SMEM_BYTES 37120         // max(CHUNK*DIM*4 = 32768, 32*145*8 = 37120)

// BIT-EXACT numpy f32 pairwise-sum of x*x for one contiguous row of 128
// floats, SIMD path with AVX512 (nlanes=16, n = 8*16 exactly -> one pass):
//   m[i]  = fl32(x[i]*x[i]);  r_b = m[16b..16b+15]
//   s     = ((r0+r1)+(r2+r3)) + ((r4+r5)+(r6+r7))      (lanewise)
//   reduce: u[i]=s[i]+s[i+8]; v[i]=u[i]+u[i+4]; w[i]=v[i]+v[i+2]; w0+w1
__device__ __forceinline__ float np_sq_avx512(const float* __restrict__ x) {
    float s[16];
    #pragma unroll
    for (int L = 0; L < 16; ++L) {
        const float m0 = __fmul_rn(x[  0 + L], x[  0 + L]);
        const float m1 = __fmul_rn(x[ 16 + L], x[ 16 + L]);
        const float m2 = __fmul_rn(x[ 32 + L], x[ 32 + L]);
        const float m3 = __fmul_rn(x[ 48 + L], x[ 48 + L]);
        const float m4 = __fmul_rn(x[ 64 + L], x[ 64 + L]);
        const float m5 = __fmul_rn(x[ 80 + L], x[ 80 + L]);
        const float m6 = __fmul_rn(x[ 96 + L], x[ 96 + L]);
        const float m7 = __fmul_rn(x[112 + L], x[112 + L]);
        s[L] = __fadd_rn(
            __fadd_rn(__fadd_rn(m0, m1), __fadd_rn(m2, m3)),
            __fadd_rn(__fadd_rn(m4, m5), __fadd_rn(m6, m7)));
    }
    float u[8];
    #pragma unroll
    for (int i = 0; i < 8; ++i) u[i] = __fadd_rn(s[i], s[i + 8]);
    float v[4];
    #pragma unroll
    for (int i = 0; i < 4; ++i) v[i] = __fadd_rn(u[i], u[i + 4]);
    const float w0 = __fadd_rn(v[0], v[2]);
    const float w1 = __fadd_rn(v[1], v[3]);
    return __fadd_rn(w0, w1);
}

__global__ __launch_bounds__(THREADS, 3)
void knn_kernel(const float* __restrict__ X, int* __restrict__ out) {
    // 37.1 KB buffer: 32 KB chunk staging during the scan; 37.1 KB packed
    // (dist32,idx) u64 keys during the epilogue (non-overlapping in time).
    __shared__ __align__(16) char smem[SMEM_BYTES];
    float* lds = (float*)smem;
    unsigned long long* keys = (unsigned long long*)smem;

    const int tid = threadIdx.x;
    const int s   = tid >> 5;       // scanner 0..7
    const int r   = tid & 31;       // row-in-block 0..31
    const int row = blockIdx.x * RPB + r;

    // own row in registers (128 VGPRs)
    float4 xi4[32];
    {
        const float4* xr = (const float4*)(X + (size_t)row * DIM);
        #pragma unroll
        for (int g = 0; g < 32; ++g) xi4[g] = xr[g];
    }

    // np-replica sq of OWN row (exact numpy-AVX512 pairwise)
    const float sqi32 = np_sq_avx512(X + (size_t)row * DIM);

    // sorted ascending top-TSEL (fp32 scan key, candidate index) — capture only
    float bv[TSEL]; int bi[TSEL];
    #pragma unroll
    for (int k = 0; k < TSEL; ++k) { bv[k] = 3.0e38f; bi[k] = 0; }

    const float4* X4 = (const float4*)X;
    float4* lds4 = (float4*)smem;

    for (int c = 0; c < NCHUNK; ++c) {
        // ---- stage chunk (coalesced linear copy: 2048 float4 / 256 thr) ----
        #pragma unroll
        for (int q = 0; q < (CHUNK * DIM / 4) / THREADS; ++q)
            lds4[tid + THREADS * q] =
                X4[(size_t)c * (CHUNK * DIM / 4) + tid + THREADS * q];
        __syncthreads();

        // ---- scan: scanner s handles j_local = s*CPS + jj ----
        #pragma unroll 1
        for (int jj = 0; jj < CPS; ++jj) {
            const int jl = s * CPS + jj;             // uniform per half-wave
            const float4* bp = (const float4*)(lds + jl * DIM);
            // 4 independent accumulators: dep chain 128 -> 32 FMA deep
            float d0 = 0.f, d1 = 0.f, d2 = 0.f, d3 = 0.f;
            #pragma unroll
            for (int g = 0; g < 32; g += 4) {        // LDS broadcast reads
                const float4 b0 = bp[g],     b1 = bp[g + 1];
                const float4 b2 = bp[g + 2], b3 = bp[g + 3];
                d0 += b0.x * xi4[g].x;     d0 += b0.y * xi4[g].y;
                d0 += b0.z * xi4[g].z;     d0 += b0.w * xi4[g].w;
                d1 += b1.x * xi4[g+1].x;   d1 += b1.y * xi4[g+1].y;
                d1 += b1.z * xi4[g+1].z;   d1 += b1.w * xi4[g+1].w;
                d2 += b2.x * xi4[g+2].x;   d2 += b2.y * xi4[g+2].y;
                d2 += b2.z * xi4[g+2].z;   d2 += b2.w * xi4[g+2].w;
                d3 += b3.x * xi4[g+3].x;   d3 += b3.y * xi4[g+3].y;
                d3 += b3.z * xi4[g+3].z;   d3 += b3.w * xi4[g+3].w;
            }
            const float dot = (d0 + d1) + (d2 + d3);
            // sq_j: 4 stride-32 reads (distinct banks) + half-wave reduce
            float p0 = lds[jl * DIM + r];
            float p1 = lds[jl * DIM + r + 32];
            float p2 = lds[jl * DIM + r + 64];
            float p3 = lds[jl * DIM + r + 96];
            float sq = p0 * p0 + p1 * p1 + p2 * p2 + p3 * p3;
            #pragma unroll
            for (int off = 16; off > 0; off >>= 1) sq += __shfl_xor(sq, off, 32);

            const float val = sq - 2.f * dot;        // capture key (noise ok)
            const int   jg  = c * CHUNK + jl;

            if (val < bv[TSEL - 1]) {                // rare after warm-up
                #pragma unroll
                for (int k = TSEL - 1; k >= 1; --k) {
                    const bool m1 = val < bv[k - 1];
                    const bool m2 = val < bv[k];
                    bv[k] = m1 ? bv[k - 1] : (m2 ? val : bv[k]);
                    bi[k] = m1 ? bi[k - 1] : (m2 ? jg  : bi[k]);
                }
                if (val < bv[0]) { bv[0] = val; bi[0] = jg; }
            }
        }
        __syncthreads();   // before next stage overwrites the buffer
    }
    // (last loop iteration ended with __syncthreads: all scans done)

    // ---- rescore: bit-replica of the np f32 pipeline (validated R9) ----
    //   sq_j : numpy pairwise-SIMD (AVX512) — np_sq_avx512 above
    //   dot  : serial k-order f32 FMA chain (OpenBLAS sgemm, 1 acc/element)
    //   d2   = fsub32( fadd32(sq_i, sq_j), fmul32(2, dot) )   [×2 exact]
    //   dist = sqrtf(max(d2,0))        [np.sqrt f32, correctly rounded]
    //   key  = (bits(dist)<<32) | idx  -> stable top_k (ties -> lower index)
    #pragma unroll
    for (int k = 0; k < TSEL; ++k) {
        const int j = bi[k];                          // register (static idx)
        unsigned long long key;
        if (j == row) {
            key = 0xFFFFFFFFFFFFFFFFULL;              // self: excluded
        } else {
            const float* xjp = X + (size_t)j * DIM;
            const float4* xj = (const float4*)xjp;
            const float sqj32 = np_sq_avx512(xjp);
            float cacc = 0.f;
            #pragma unroll
            for (int g = 0; g < 32; ++g) {
                const float4 a = xi4[g], b = xj[g];
                cacc = __fmaf_rn(a.x, b.x, cacc);
                cacc = __fmaf_rn(a.y, b.y, cacc);
                cacc = __fmaf_rn(a.z, b.z, cacc);
                cacc = __fmaf_rn(a.w, b.w, cacc);
            }
            float d2c = __fsub_rn(__fadd_rn(sqi32, sqj32),
                                  __fmul_rn(2.0f, cacc));
            if (d2c < 0.0f) d2c = 0.0f;
            const float dist32 = sqrtf(d2c);          // f32 sqrt, correct rnd
            key = ((unsigned long long)__float_as_uint(dist32) << 32)
                  | (unsigned int)j;
        }
        keys[r * CSTRIDE + s * TSEL + k] = key;
    }
    __syncthreads();

    // ---- per-row top-16 by packed key ----
    if (tid < 32) {
        const int base = tid * CSTRIDE;
        const int i = blockIdx.x * RPB + tid;
        for (int m = 0; m < KSEL; ++m) {
            unsigned long long best = 0xFFFFFFFFFFFFFFFFULL; int bc = 0;
            for (int c2 = 0; c2 < NCAND; ++c2) {
                const unsigned long long v = keys[base + c2];
                if (v < best) { best = v; bc = c2; }
            }
            out[(size_t)i * KSEL + m] = (int)(best & 0xFFFFFFFFULL);
            keys[base + bc] = 0xFFFFFFFFFFFFFFFFULL;  // remove picked
        }
    }
}

extern "C" void kernel_launch(void* const* d_in, const int* in_sizes, int n_in,
                              void* d_out, int out_size, void* d_ws, size_t ws_size,
                              hipStream_t stream) {
    (void)in_sizes; (void)n_in; (void)out_size; (void)d_ws; (void)ws_size;
    const float* X = (const float*)d_in[0];
    int* out = (int*)d_out;
    knn_kernel<<<dim3(NPTS / RPB), dim3(THREADS), 0, stream>>>(X, out);
}

// Round 11
// 3975.853 us; speedup vs baseline: 3.3796x; 3.3796x over previous
//
#include <hip/hip_runtime.h>
#include <math.h>

#define NPTS    16384
#define DIM     128
#define KSEL    16
#define TSEL    18      // per-scanner sorted top list (16 + self + 1 margin)
#define NSCAN   8       // scanners per row (one per half-wave)
#define RPB     32      // rows per block
#define THREADS 256
#define CHUNK   64      // candidate columns staged per LDS chunk (32 KB)
#define NCHUNK  (NPTS / CHUNK)
#define CPS     (CHUNK / NSCAN)  // candidates per scanner per chunk = 8
#define NCAND   (NSCAN * TSEL)   // 144 candidates per row
#define CSTRIDE 145              // padded per-row stride (u64 keys)
#define SMEM_BYTES 37120         // max(CHUNK*DIM*4 = 32768, 32*145*8 = 37120)

// BIT-EXACT numpy f32 pairwise-sum of x*x for one contiguous row of 128
// floats, SIMD path with AVX512 (nlanes=16, n = 8*16 exactly -> one pass):
//   m[i]  = fl32(x[i]*x[i]);  r_b = m[16b..16b+15]
//   s     = ((r0+r1)+(r2+r3)) + ((r4+r5)+(r6+r7))      (lanewise)
//   reduce: u[i]=s[i]+s[i+8]; v[i]=u[i]+u[i+4]; w[i]=v[i]+v[i+2]; w0+w1
__device__ __forceinline__ float np_sq_avx512(const float* __restrict__ x) {
    float s[16];
    #pragma unroll
    for (int L = 0; L < 16; ++L) {
        const float m0 = __fmul_rn(x[  0 + L], x[  0 + L]);
        const float m1 = __fmul_rn(x[ 16 + L], x[ 16 + L]);
        const float m2 = __fmul_rn(x[ 32 + L], x[ 32 + L]);
        const float m3 = __fmul_rn(x[ 48 + L], x[ 48 + L]);
        const float m4 = __fmul_rn(x[ 64 + L], x[ 64 + L]);
        const float m5 = __fmul_rn(x[ 80 + L], x[ 80 + L]);
        const float m6 = __fmul_rn(x[ 96 + L], x[ 96 + L]);
        const float m7 = __fmul_rn(x[112 + L], x[112 + L]);
        s[L] = __fadd_rn(
            __fadd_rn(__fadd_rn(m0, m1), __fadd_rn(m2, m3)),
            __fadd_rn(__fadd_rn(m4, m5), __fadd_rn(m6, m7)));
    }
    float u[8];
    #pragma unroll
    for (int i = 0; i < 8; ++i) u[i] = __fadd_rn(s[i], s[i + 8]);
    float v[4];
    #pragma unroll
    for (int i = 0; i < 4; ++i) v[i] = __fadd_rn(u[i], u[i + 4]);
    const float w0 = __fadd_rn(v[0], v[2]);
    const float w1 = __fadd_rn(v[1], v[3]);
    return __fadd_rn(w0, w1);
}

// launch_bounds(256,2): the R9-proven spill-free setting. (,3) made the
// compiler cap VGPRs at 84 -> xi4[32] spilled to scratch -> 38.5 GB HBM
// traffic and 2.8x regression. Do not raise the min-waves bound.
__global__ __launch_bounds__(THREADS, 2)
void knn_kernel(const float* __restrict__ X, int* __restrict__ out) {
    // 37.1 KB buffer: 32 KB chunk staging during the scan; 37.1 KB packed
    // (dist32,idx) u64 keys during the epilogue (non-overlapping in time).
    __shared__ __align__(16) char smem[SMEM_BYTES];
    float* lds = (float*)smem;
    unsigned long long* keys = (unsigned long long*)smem;

    const int tid = threadIdx.x;
    const int s   = tid >> 5;       // scanner 0..7
    const int r   = tid & 31;       // row-in-block 0..31
    const int row = blockIdx.x * RPB + r;

    // own row in registers (128 VGPRs)
    float4 xi4[32];
    {
        const float4* xr = (const float4*)(X + (size_t)row * DIM);
        #pragma unroll
        for (int g = 0; g < 32; ++g) xi4[g] = xr[g];
    }

    // np-replica sq of OWN row (exact numpy-AVX512 pairwise)
    const float sqi32 = np_sq_avx512(X + (size_t)row * DIM);

    // sorted ascending top-TSEL (fp32 scan key, candidate index) — capture only
    float bv[TSEL]; int bi[TSEL];
    #pragma unroll
    for (int k = 0; k < TSEL; ++k) { bv[k] = 3.0e38f; bi[k] = 0; }

    const float4* X4 = (const float4*)X;
    float4* lds4 = (float4*)smem;

    for (int c = 0; c < NCHUNK; ++c) {
        // ---- stage chunk (coalesced linear copy: 2048 float4 / 256 thr) ----
        #pragma unroll
        for (int q = 0; q < (CHUNK * DIM / 4) / THREADS; ++q)
            lds4[tid + THREADS * q] =
                X4[(size_t)c * (CHUNK * DIM / 4) + tid + THREADS * q];
        __syncthreads();

        // ---- scan: scanner s handles j_local = s*CPS + jj ----
        #pragma unroll 1
        for (int jj = 0; jj < CPS; ++jj) {
            const int jl = s * CPS + jj;             // uniform per half-wave
            const float4* bp = (const float4*)(lds + jl * DIM);
            // 4 independent accumulators: dep chain 128 -> 32 FMA deep
            float d0 = 0.f, d1 = 0.f, d2 = 0.f, d3 = 0.f;
            #pragma unroll
            for (int g = 0; g < 32; g += 4) {        // LDS broadcast reads
                const float4 b0 = bp[g],     b1 = bp[g + 1];
                const float4 b2 = bp[g + 2], b3 = bp[g + 3];
                d0 += b0.x * xi4[g].x;     d0 += b0.y * xi4[g].y;
                d0 += b0.z * xi4[g].z;     d0 += b0.w * xi4[g].w;
                d1 += b1.x * xi4[g+1].x;   d1 += b1.y * xi4[g+1].y;
                d1 += b1.z * xi4[g+1].z;   d1 += b1.w * xi4[g+1].w;
                d2 += b2.x * xi4[g+2].x;   d2 += b2.y * xi4[g+2].y;
                d2 += b2.z * xi4[g+2].z;   d2 += b2.w * xi4[g+2].w;
                d3 += b3.x * xi4[g+3].x;   d3 += b3.y * xi4[g+3].y;
                d3 += b3.z * xi4[g+3].z;   d3 += b3.w * xi4[g+3].w;
            }
            const float dot = (d0 + d1) + (d2 + d3);
            // sq_j: 4 stride-32 reads (distinct banks) + half-wave reduce
            float p0 = lds[jl * DIM + r];
            float p1 = lds[jl * DIM + r + 32];
            float p2 = lds[jl * DIM + r + 64];
            float p3 = lds[jl * DIM + r + 96];
            float sq = p0 * p0 + p1 * p1 + p2 * p2 + p3 * p3;
            #pragma unroll
            for (int off = 16; off > 0; off >>= 1) sq += __shfl_xor(sq, off, 32);

            const float val = sq - 2.f * dot;        // capture key (noise ok)
            const int   jg  = c * CHUNK + jl;

            if (val < bv[TSEL - 1]) {                // rare after warm-up
                #pragma unroll
                for (int k = TSEL - 1; k >= 1; --k) {
                    const bool m1 = val < bv[k - 1];
                    const bool m2 = val < bv[k];
                    bv[k] = m1 ? bv[k - 1] : (m2 ? val : bv[k]);
                    bi[k] = m1 ? bi[k - 1] : (m2 ? jg  : bi[k]);
                }
                if (val < bv[0]) { bv[0] = val; bi[0] = jg; }
            }
        }
        __syncthreads();   // before next stage overwrites the buffer
    }
    // (last loop iteration ended with __syncthreads: all scans done)

    // ---- rescore: bit-replica of the np f32 pipeline (validated R9) ----
    //   sq_j : numpy pairwise-SIMD (AVX512) — np_sq_avx512 above
    //   dot  : serial k-order f32 FMA chain (OpenBLAS sgemm, 1 acc/element)
    //   d2   = fsub32( fadd32(sq_i, sq_j), fmul32(2, dot) )   [×2 exact]
    //   dist = sqrtf(max(d2,0))        [np.sqrt f32, correctly rounded]
    //   key  = (bits(dist)<<32) | idx  -> stable top_k (ties -> lower index)
    #pragma unroll
    for (int k = 0; k < TSEL; ++k) {
        const int j = bi[k];                          // register (static idx)
        unsigned long long key;
        if (j == row) {
            key = 0xFFFFFFFFFFFFFFFFULL;              // self: excluded
        } else {
            const float* xjp = X + (size_t)j * DIM;
            const float4* xj = (const float4*)xjp;
            const float sqj32 = np_sq_avx512(xjp);
            float cacc = 0.f;
            #pragma unroll
            for (int g = 0; g < 32; ++g) {
                const float4 a = xi4[g], b = xj[g];
                cacc = __fmaf_rn(a.x, b.x, cacc);
                cacc = __fmaf_rn(a.y, b.y, cacc);
                cacc = __fmaf_rn(a.z, b.z, cacc);
                cacc = __fmaf_rn(a.w, b.w, cacc);
            }
            float d2c = __fsub_rn(__fadd_rn(sqi32, sqj32),
                                  __fmul_rn(2.0f, cacc));
            if (d2c < 0.0f) d2c = 0.0f;
            const float dist32 = sqrtf(d2c);          // f32 sqrt, correct rnd
            key = ((unsigned long long)__float_as_uint(dist32) << 32)
                  | (unsigned int)j;
        }
        keys[r * CSTRIDE + s * TSEL + k] = key;
    }
    __syncthreads();

    // ---- per-row top-16 by packed key ----
    if (tid < 32) {
        const int base = tid * CSTRIDE;
        const int i = blockIdx.x * RPB + tid;
        for (int m = 0; m < KSEL; ++m) {
            unsigned long long best = 0xFFFFFFFFFFFFFFFFULL; int bc = 0;
            for (int c2 = 0; c2 < NCAND; ++c2) {
                const unsigned long long v = keys[base + c2];
                if (v < best) { best = v; bc = c2; }
            }
            out[(size_t)i * KSEL + m] = (int)(best & 0xFFFFFFFFULL);
            keys[base + bc] = 0xFFFFFFFFFFFFFFFFULL;  // remove picked
        }
    }
}

extern "C" void kernel_launch(void* const* d_in, const int* in_sizes, int n_in,
                              void* d_out, int out_size, void* d_ws, size_t ws_size,
                              hipStream_t stream) {
    (void)in_sizes; (void)n_in; (void)out_size; (void)d_ws; (void)ws_size;
    const float* X = (const float*)d_in[0];
    int* out = (int*)d_out;
    knn_kernel<<<dim3(NPTS / RPB), dim3(THREADS), 0, stream>>>(X, out);
}